// Round 12
// baseline (225.315 us; speedup 1.0000x reference)
//
#include <hip/hip_runtime.h>
#include <stdint.h>

#define NN 16384
#define NE 128

typedef __attribute__((ext_vector_type(8))) short bf16x8;
typedef __attribute__((ext_vector_type(4))) float f32x4;
typedef uint32_t __attribute__((address_space(1))) gl_u32;
typedef uint32_t __attribute__((address_space(3))) lds_u32;

__device__ __forceinline__ uint32_t pack_bf16_2(float a, float b){
  union { float f; uint32_t u; } ua, ub;
  ua.f = a; ub.f = b;
  uint32_t x = ua.u, y = ub.u;
  x = (x + 0x7fffu + ((x >> 16) & 1u)) >> 16;   // RNE
  y = (y + 0x7fffu + ((y >> 16) & 1u)) >> 16;
  return (x & 0xffffu) | (y << 16);
}

// A [NN][NE] fp32 -> Ab [NN][NE] bf16
__global__ void conv_a_kernel(const float4* __restrict__ A, uint4* __restrict__ Ab){
  size_t t = (size_t)blockIdx.x * blockDim.x + threadIdx.x;
  float4 a = A[2*t], b = A[2*t+1];
  uint4 o;
  o.x = pack_bf16_2(a.x, a.y);
  o.y = pack_bf16_2(a.z, a.w);
  o.z = pack_bf16_2(b.x, b.y);
  o.w = pack_bf16_2(b.z, b.w);
  Ab[t] = o;
}

// B [NE][NN] fp32 + W[NE] -> Bt [NN][NE] bf16, Bt[n][k] = bf16(W[k]*B[k][n])
__global__ void conv_bt_kernel(const float* __restrict__ B, const float* __restrict__ W,
                               uint4* __restrict__ Bt){
  int n = blockIdx.x * 256 + threadIdx.x;
  #pragma unroll
  for (int kc = 0; kc < 16; ++kc){
    float f[8];
    #pragma unroll
    for (int j = 0; j < 8; ++j){
      int k = kc*8 + j;
      f[j] = W[k] * B[(size_t)k * NN + n];    // coalesced along n
    }
    uint4 o;
    o.x = pack_bf16_2(f[0], f[1]);
    o.y = pack_bf16_2(f[2], f[3]);
    o.z = pack_bf16_2(f[4], f[5]);
    o.w = pack_bf16_2(f[6], f[7]);
    Bt[(size_t)n * 16 + kc] = o;
  }
}

// R12 = R7 (best, 217.6/218.1us reproduced) + ONE isolated change: swapped
// MFMA operands -> transposed D fragment -> each lane's 4 acc regs span 4
// consecutive n -> one aligned dwordx4 store per fragment (8 insts/thread vs
// 32). Clean isolation of R4's confounded swap test (NT stores + grid change
// removed). Tests whether epilogue VMEM issue pressure is a secondary cost;
// byte-limited drain predicts ~neutral, in which case R7 is the ceiling.
// Everything else identical to R7: 128x64 tile, 48KB LDS, 3 blocks/CU,
// XOR-swizzled LDS + gload_lds w16, GM=16 m-fastest grouping.
__launch_bounds__(256, 3)
__global__ void gemm_kernel(const uint4* __restrict__ Ab, const uint4* __restrict__ Bt,
                            float* __restrict__ C){
  __shared__ uint4 lds[3072];            // 48 KB: [0..2047] A 128rows, [2048..3071] B 64rows
  const int tid  = threadIdx.x;
  const int lane = tid & 63;
  const int bid  = blockIdx.x;
  const int grp  = bid >> 12;            // bid / (16*256): 8 groups
  const int r    = bid & 4095;
  const int m0   = (((grp << 4) + (r & 15)) << 7);   // m iterates fastest within group
  const int n0   = ((r >> 4) << 6);                  // 256 n-panels of 64

  // stage A-tile (8 chunks/thread) + B-tile (4 chunks/thread), swizzled source
  #pragma unroll
  for (int i = 0; i < 8; ++i){
    int cid = (i << 8) + tid;            // 0..2047 : row = cid>>4, g = cid&15
    int row = cid >> 4;
    int gs  = (cid & 15) ^ (row & 7);
    __builtin_amdgcn_global_load_lds((const gl_u32*)(Ab + (((size_t)(m0 + row)) << 4) + gs),
                                     (lds_u32*)&lds[cid], 16, 0, 0);
  }
  #pragma unroll
  for (int i = 0; i < 4; ++i){
    int cid = (i << 8) + tid;            // 0..1023 : row = cid>>4, g = cid&15
    int row = cid >> 4;
    int gs  = (cid & 15) ^ (row & 7);
    __builtin_amdgcn_global_load_lds((const gl_u32*)(Bt + (((size_t)(n0 + row)) << 4) + gs),
                                     (lds_u32*)&lds[2048 + cid], 16, 0, 0);
  }
  __syncthreads();                       // drains vmcnt -> LDS data visible

  const int w   = tid >> 6;
  const int wm  = (w >> 1) << 6;         // wave's 64-row block (2x2 wave grid)
  const int wn  = (w & 1) << 5;          // wave's 32-col block
  const int l15 = lane & 15;
  const int l4  = lane >> 4;

  f32x4 acc[4][2];
  #pragma unroll
  for (int i = 0; i < 4; ++i)
    #pragma unroll
    for (int j = 0; j < 2; ++j)
      acc[i][j] = (f32x4){0.f, 0.f, 0.f, 0.f};

  #pragma unroll
  for (int ks = 0; ks < 4; ++ks){        // K = 4 x 32
    bf16x8 af[4], bfr[2];
    const int c = (ks << 2) + l4;        // logical 16B chunk = 8 k-values
    #pragma unroll
    for (int mt = 0; mt < 4; ++mt){
      int row = wm + (mt << 4) + l15;    // A row (lane&15 = M index)
      af[mt] = *reinterpret_cast<const bf16x8*>(&lds[(row << 4) + (c ^ (row & 7))]);
    }
    #pragma unroll
    for (int nt = 0; nt < 2; ++nt){
      int row = wn + (nt << 4) + l15;    // Bt row (lane&15 = N index)
      bfr[nt] = *reinterpret_cast<const bf16x8*>(&lds[2048 + (row << 4) + (c ^ (row & 7))]);
    }
    // Swapped: D = B_frag x A_frag -> col(lane&15)=m, row((lane>>4)*4+reg)=n.
    #pragma unroll
    for (int mt = 0; mt < 4; ++mt)
      #pragma unroll
      for (int nt = 0; nt < 2; ++nt)
        acc[mt][nt] = __builtin_amdgcn_mfma_f32_16x16x32_bf16(bfr[nt], af[mt], acc[mt][nt], 0, 0, 0);
  }

  // Transposed-D epilogue: m = ...+l15 (fixed per lane), n = ...+(l4<<2)+reg
  // -> one aligned float4 store per (mt,nt). 8 dwordx4 insts/thread.
  #pragma unroll
  for (int mt = 0; mt < 4; ++mt){
    #pragma unroll
    for (int nt = 0; nt < 2; ++nt){
      size_t row = (size_t)(m0 + wm + (mt << 4) + l15);
      float* p = C + row * NN + (size_t)(n0 + wn + (nt << 4) + (l4 << 2));
      *reinterpret_cast<f32x4*>(p) = acc[mt][nt];
    }
  }
}

// correctness fallback if workspace is too small (fp32 vector math, slow but exact-path)
__global__ void gemm_fallback(const float* __restrict__ A, const float* __restrict__ B,
                              const float* __restrict__ W, float* __restrict__ C){
  int n = blockIdx.x * 16 + threadIdx.x;
  int m = blockIdx.y * 16 + threadIdx.y;
  float acc = 0.f;
  for (int k = 0; k < NE; ++k)
    acc += A[(size_t)m * NE + k] * (W[k] * B[(size_t)k * NN + n]);
  C[(size_t)m * NN + n] = acc;
}

extern "C" void kernel_launch(void* const* d_in, const int* in_sizes, int n_in,
                              void* d_out, int out_size, void* d_ws, size_t ws_size,
                              hipStream_t stream){
  const float* A = (const float*)d_in[0];   // DV2_H [NN][NE]
  const float* B = (const float*)d_in[1];   // invDE_HT_DV2 [NE][NN]
  const float* W = (const float*)d_in[2];   // [NE]
  float* C = (float*)d_out;                 // [NN][NN] fp32

  const size_t need = (size_t)NN * NE * 2 * 2;   // Ab + Bt, 8 MB
  if (ws_size >= need){
    uint4* Ab = (uint4*)d_ws;
    uint4* Bt = (uint4*)((char*)d_ws + (size_t)NN * NE * 2);
    conv_a_kernel<<<NN * NE / (256 * 8), 256, 0, stream>>>((const float4*)A, Ab);
    conv_bt_kernel<<<NN / 256, 256, 0, stream>>>(B, W, Bt);
    gemm_kernel<<<(NN / 128) * (NN / 64), 256, 0, stream>>>(Ab, Bt, C);
  } else {
    dim3 g(NN / 16, NN / 16), b(16, 16);
    gemm_fallback<<<g, b, 0, stream>>>(A, B, W, C);
  }
}

// Round 13
// 217.798 us; speedup vs baseline: 1.0345x; 1.0345x over previous
//
#include <hip/hip_runtime.h>
#include <stdint.h>

#define NN 16384
#define NE 128

typedef __attribute__((ext_vector_type(8))) short bf16x8;
typedef __attribute__((ext_vector_type(4))) float f32x4;
typedef uint32_t __attribute__((address_space(1))) gl_u32;
typedef uint32_t __attribute__((address_space(3))) lds_u32;

__device__ __forceinline__ uint32_t pack_bf16_2(float a, float b){
  union { float f; uint32_t u; } ua, ub;
  ua.f = a; ub.f = b;
  uint32_t x = ua.u, y = ub.u;
  x = (x + 0x7fffu + ((x >> 16) & 1u)) >> 16;   // RNE
  y = (y + 0x7fffu + ((y >> 16) & 1u)) >> 16;
  return (x & 0xffffu) | (y << 16);
}

// A [NN][NE] fp32 -> Ab [NN][NE] bf16
__global__ void conv_a_kernel(const float4* __restrict__ A, uint4* __restrict__ Ab){
  size_t t = (size_t)blockIdx.x * blockDim.x + threadIdx.x;
  float4 a = A[2*t], b = A[2*t+1];
  uint4 o;
  o.x = pack_bf16_2(a.x, a.y);
  o.y = pack_bf16_2(a.z, a.w);
  o.z = pack_bf16_2(b.x, b.y);
  o.w = pack_bf16_2(b.z, b.w);
  Ab[t] = o;
}

// B [NE][NN] fp32 + W[NE] -> Bt [NN][NE] bf16, Bt[n][k] = bf16(W[k]*B[k][n])
__global__ void conv_bt_kernel(const float* __restrict__ B, const float* __restrict__ W,
                               uint4* __restrict__ Bt){
  int n = blockIdx.x * 256 + threadIdx.x;
  #pragma unroll
  for (int kc = 0; kc < 16; ++kc){
    float f[8];
    #pragma unroll
    for (int j = 0; j < 8; ++j){
      int k = kc*8 + j;
      f[j] = W[k] * B[(size_t)k * NN + n];    // coalesced along n
    }
    uint4 o;
    o.x = pack_bf16_2(f[0], f[1]);
    o.y = pack_bf16_2(f[2], f[3]);
    o.z = pack_bf16_2(f[4], f[5]);
    o.w = pack_bf16_2(f[6], f[7]);
    Bt[(size_t)n * 16 + kc] = o;
  }
}

// FINAL (R7 structure; best of 12 experiments: 217.6/218.1us reproduced,
// ~5.1 TB/s effective = 78% of the co-measured pure-write fill ceiling).
// 128x64 tile -> 48KB LDS -> 3 blocks/CU (occupancy bracketed: 2=227, 3=218,
// 5=249). XOR-swizzled LDS fed by global_load_lds width=16 (linear dest,
// inverse-swizzled source, swizzled ds_read_b128 -> 0 bank conflicts).
// GM=16 m-fastest grid grouping keeps the group's Ab slice + shared Bt panel
// L2-hot (+10us vs naive). Direct dword C-stores: 4 consecutive insts cover a
// contiguous 256B row span; L2 write-back assembles full lines (beats
// LDS-transpose epilogue, NT stores, and both swapped-operand epilogues).
__launch_bounds__(256, 3)
__global__ void gemm_kernel(const uint4* __restrict__ Ab, const uint4* __restrict__ Bt,
                            float* __restrict__ C){
  __shared__ uint4 lds[3072];            // 48 KB: [0..2047] A 128rows, [2048..3071] B 64rows
  const int tid  = threadIdx.x;
  const int lane = tid & 63;
  const int bid  = blockIdx.x;
  const int grp  = bid >> 12;            // bid / (16*256): 8 groups
  const int r    = bid & 4095;
  const int m0   = (((grp << 4) + (r & 15)) << 7);   // m iterates fastest within group
  const int n0   = ((r >> 4) << 6);                  // 256 n-panels of 64

  // stage A-tile (8 chunks/thread) + B-tile (4 chunks/thread), swizzled source
  #pragma unroll
  for (int i = 0; i < 8; ++i){
    int cid = (i << 8) + tid;            // 0..2047 : row = cid>>4, g = cid&15
    int row = cid >> 4;
    int gs  = (cid & 15) ^ (row & 7);
    __builtin_amdgcn_global_load_lds((const gl_u32*)(Ab + (((size_t)(m0 + row)) << 4) + gs),
                                     (lds_u32*)&lds[cid], 16, 0, 0);
  }
  #pragma unroll
  for (int i = 0; i < 4; ++i){
    int cid = (i << 8) + tid;            // 0..1023 : row = cid>>4, g = cid&15
    int row = cid >> 4;
    int gs  = (cid & 15) ^ (row & 7);
    __builtin_amdgcn_global_load_lds((const gl_u32*)(Bt + (((size_t)(n0 + row)) << 4) + gs),
                                     (lds_u32*)&lds[2048 + cid], 16, 0, 0);
  }
  __syncthreads();                       // drains vmcnt -> LDS data visible

  const int w   = tid >> 6;
  const int wm  = (w >> 1) << 6;         // wave's 64-row block (2x2 wave grid)
  const int wn  = (w & 1) << 5;          // wave's 32-col block
  const int l15 = lane & 15;
  const int l4  = lane >> 4;

  f32x4 acc[4][2];
  #pragma unroll
  for (int i = 0; i < 4; ++i)
    #pragma unroll
    for (int j = 0; j < 2; ++j)
      acc[i][j] = (f32x4){0.f, 0.f, 0.f, 0.f};

  #pragma unroll
  for (int ks = 0; ks < 4; ++ks){        // K = 4 x 32
    bf16x8 af[4], bfr[2];
    const int c = (ks << 2) + l4;        // logical 16B chunk = 8 k-values
    #pragma unroll
    for (int mt = 0; mt < 4; ++mt){
      int row = wm + (mt << 4) + l15;    // A row (lane&15 = M index)
      af[mt] = *reinterpret_cast<const bf16x8*>(&lds[(row << 4) + (c ^ (row & 7))]);
    }
    #pragma unroll
    for (int nt = 0; nt < 2; ++nt){
      int row = wn + (nt << 4) + l15;    // Bt row (lane&15 = N index)
      bfr[nt] = *reinterpret_cast<const bf16x8*>(&lds[2048 + (row << 4) + (c ^ (row & 7))]);
    }
    #pragma unroll
    for (int mt = 0; mt < 4; ++mt)
      #pragma unroll
      for (int nt = 0; nt < 2; ++nt)
        acc[mt][nt] = __builtin_amdgcn_mfma_f32_16x16x32_bf16(af[mt], bfr[nt], acc[mt][nt], 0, 0, 0);
  }

  // C/D layout: col = lane&15 (n), row = (lane>>4)*4 + reg (m).
  #pragma unroll
  for (int mt = 0; mt < 4; ++mt){
    #pragma unroll
    for (int j = 0; j < 4; ++j){
      size_t row = (size_t)(m0 + wm + (mt << 4) + (l4 << 2) + j);
      float* crow = C + row * NN + (size_t)(n0 + wn + l15);
      #pragma unroll
      for (int nt = 0; nt < 2; ++nt)
        crow[nt << 4] = acc[mt][nt][j];
    }
  }
}

// correctness fallback if workspace is too small (fp32 vector math, slow but exact-path)
__global__ void gemm_fallback(const float* __restrict__ A, const float* __restrict__ B,
                              const float* __restrict__ W, float* __restrict__ C){
  int n = blockIdx.x * 16 + threadIdx.x;
  int m = blockIdx.y * 16 + threadIdx.y;
  float acc = 0.f;
  for (int k = 0; k < NE; ++k)
    acc += A[(size_t)m * NE + k] * (W[k] * B[(size_t)k * NN + n]);
  C[(size_t)m * NN + n] = acc;
}

extern "C" void kernel_launch(void* const* d_in, const int* in_sizes, int n_in,
                              void* d_out, int out_size, void* d_ws, size_t ws_size,
                              hipStream_t stream){
  const float* A = (const float*)d_in[0];   // DV2_H [NN][NE]
  const float* B = (const float*)d_in[1];   // invDE_HT_DV2 [NE][NN]
  const float* W = (const float*)d_in[2];   // [NE]
  float* C = (float*)d_out;                 // [NN][NN] fp32

  const size_t need = (size_t)NN * NE * 2 * 2;   // Ab + Bt, 8 MB
  if (ws_size >= need){
    uint4* Ab = (uint4*)d_ws;
    uint4* Bt = (uint4*)((char*)d_ws + (size_t)NN * NE * 2);
    conv_a_kernel<<<NN * NE / (256 * 8), 256, 0, stream>>>((const float4*)A, Ab);
    conv_bt_kernel<<<NN / 256, 256, 0, stream>>>(B, W, Bt);
    gemm_kernel<<<(NN / 128) * (NN / 64), 256, 0, stream>>>(Ab, Bt, C);
  } else {
    dim3 g(NN / 16, NN / 16), b(16, 16);
    gemm_fallback<<<g, b, 0, stream>>>(A, B, W, C);
  }
}